// Round 15
// baseline (398.827 us; speedup 1.0000x reference)
//
#include <hip/hip_runtime.h>
#include <hip/hip_bf16.h>
#include <math.h>

typedef __attribute__((ext_vector_type(8))) short bf16x8;
typedef __attribute__((ext_vector_type(4))) float f32x4;

#define CAP 8192   // per-bucket capacity (mean 4096, sigma 64 -> no overflow)

// ============ bf16 pack/unpack helpers (bit ops, RNE) ============
__device__ __forceinline__ unsigned pk_bf16(float lo, float hi) {
    unsigned a = __float_as_uint(lo), b = __float_as_uint(hi);
    unsigned alo = (a + 0x7fffu + ((a >> 16) & 1u)) >> 16;
    unsigned bhi = (b + 0x7fffu + ((b >> 16) & 1u)) >> 16;
    return alo | (bhi << 16);
}
__device__ __forceinline__ float bf_lo(unsigned u) { return __uint_as_float(u << 16); }
__device__ __forceinline__ float bf_hi(unsigned u) { return __uint_as_float(u & 0xffff0000u); }

// Bucket = 128 dst nodes. ebuf entry: (dloc<<17) | src   (needs N < 131072)

// ============ ONE-PASS bucketing: LDS hist -> global range-reserve -> scatter ============
__global__ __launch_bounds__(256) void k_place1(
    const int* __restrict__ src, const int* __restrict__ dst,
    int* __restrict__ gcur, unsigned* __restrict__ ebuf,
    int E, int B, int CHUNK)
{
    __shared__ int hist[1024];
    __shared__ int curb[1024];
    int tid = threadIdx.x, b = blockIdx.x;
    for (int j = tid; j < B; j += 256) hist[j] = 0;
    __syncthreads();
    int e0 = b * CHUNK, e1 = min(e0 + CHUNK, E);
    for (int i = e0 + tid * 4; i < e1; i += 1024) {
        if (i + 3 < e1) {
            int4 d4 = *(const int4*)(dst + i);
            atomicAdd(&hist[d4.x >> 7], 1);
            atomicAdd(&hist[d4.y >> 7], 1);
            atomicAdd(&hist[d4.z >> 7], 1);
            atomicAdd(&hist[d4.w >> 7], 1);
        } else {
            for (int k = i; k < e1; ++k) atomicAdd(&hist[dst[k] >> 7], 1);
        }
    }
    __syncthreads();
    for (int j = tid; j < B; j += 256) {
        int h = hist[j];
        curb[j] = h ? atomicAdd(&gcur[j], h) : 0;   // reserve [base, base+h) in bucket j
    }
    __syncthreads();
    for (int i = e0 + tid * 4; i < e1; i += 1024) {
        if (i + 3 < e1) {
            int4 d4 = *(const int4*)(dst + i);
            int4 s4 = *(const int4*)(src + i);
            int p0 = atomicAdd(&curb[d4.x >> 7], 1);
            int p1 = atomicAdd(&curb[d4.y >> 7], 1);
            int p2 = atomicAdd(&curb[d4.z >> 7], 1);
            int p3 = atomicAdd(&curb[d4.w >> 7], 1);
            ebuf[(size_t)(d4.x >> 7) * CAP + p0] = ((unsigned)(d4.x & 127) << 17) | (unsigned)s4.x;
            ebuf[(size_t)(d4.y >> 7) * CAP + p1] = ((unsigned)(d4.y & 127) << 17) | (unsigned)s4.y;
            ebuf[(size_t)(d4.z >> 7) * CAP + p2] = ((unsigned)(d4.z & 127) << 17) | (unsigned)s4.z;
            ebuf[(size_t)(d4.w >> 7) * CAP + p3] = ((unsigned)(d4.w & 127) << 17) | (unsigned)s4.w;
        } else {
            for (int k = i; k < e1; ++k) {
                int d = dst[k], s = src[k];
                int pos = atomicAdd(&curb[d >> 7], 1);
                ebuf[(size_t)(d >> 7) * CAP + pos] = ((unsigned)(d & 127) << 17) | (unsigned)s;
            }
        }
    }
}

// ============ per-bucket CSR build -> csr (CAP-strided), odeg=(offs,deg), dinv ============
__global__ __launch_bounds__(256) void k_csr(
    const int* __restrict__ gcur, const unsigned* __restrict__ ebuf,
    int* __restrict__ csr, int2* __restrict__ odeg,
    float* __restrict__ dinv, int N)
{
    __shared__ int sm[128];
    __shared__ int loc[128];
    int j = blockIdx.x, tid = threadIdx.x;
    int e0 = j * CAP;
    int e1 = e0 + gcur[j];
    if (tid < 128) sm[tid] = 0;
    __syncthreads();
    for (int i = e0 + tid; i < e1; i += 256) atomicAdd(&sm[ebuf[i] >> 17], 1);
    __syncthreads();
    int v = (tid < 128) ? sm[tid] : 0;
    for (int off = 1; off < 128; off <<= 1) {
        int t = (tid < 128 && tid >= off) ? sm[tid - off] : 0;
        __syncthreads();
        if (tid < 128) sm[tid] += t;
        __syncthreads();
    }
    if (tid < 128) {
        int ex = sm[tid] - v;
        loc[tid] = e0 + ex;
        int n = j * 128 + tid;
        if (n < N) {
            odeg[n] = make_int2(e0 + ex, v);
            dinv[n] = rsqrtf((float)v + 1.0f);
        }
    }
    __syncthreads();
    for (int i = e0 + tid; i < e1; i += 256) {
        unsigned eb = ebuf[i];
        int pos = atomicAdd(&loc[eb >> 17], 1);
        csr[pos] = (int)(eb & 0x1FFFFu);
    }
}

// ============ GEMM1 (MFMA, R11 known-good): h1s = (x @ W1) * dinv ============
__global__ __launch_bounds__(256) void k_gemm1(
    const float* __restrict__ x, const float* __restrict__ W1,
    const float* __restrict__ dinv, unsigned* __restrict__ h1s, int N)
{
    const int lane = threadIdx.x & 63;
    const int wid  = threadIdx.x >> 6;
    const int gwave  = blockIdx.x * 4 + wid;
    const int nwaves = gridDim.x * 4;
    const int col = lane & 15;
    const int kg  = lane >> 4;

    unsigned bfr[16][4];
    #pragma unroll
    for (int kk = 0; kk < 16; ++kk) {
        int kbase = kk * 32 + kg * 8;
        #pragma unroll
        for (int i = 0; i < 4; ++i) {
            float lo = W1[(size_t)(kbase + 2 * i) * 16 + col];
            float hi = W1[(size_t)(kbase + 2 * i + 1) * 16 + col];
            bfr[kk][i] = pk_bf16(lo, hi);
        }
    }

    const int TT = N >> 4;
    for (int t = gwave; t < TT; t += nwaves) {
        const float* xr = x + (size_t)(t * 16 + col) * 512 + kg * 8;
        f32x4 acc = {0.f, 0.f, 0.f, 0.f};
        #pragma unroll
        for (int kk = 0; kk < 16; ++kk) {
            float4 xa = *(const float4*)(xr + kk * 32);
            float4 xb = *(const float4*)(xr + kk * 32 + 4);
            unsigned afr[4];
            afr[0] = pk_bf16(xa.x, xa.y);
            afr[1] = pk_bf16(xa.z, xa.w);
            afr[2] = pk_bf16(xb.x, xb.y);
            afr[3] = pk_bf16(xb.z, xb.w);
            acc = __builtin_amdgcn_mfma_f32_16x16x32_bf16(
                *(bf16x8*)afr, *(bf16x8*)&bfr[kk][0], acc, 0, 0, 0);
        }
        #pragma unroll
        for (int m = 0; m < 4; ++m) {
            int r = t * 16 + kg * 4 + m;
            float v = acc[m] * dinv[r];
            float oth = __shfl_xor(v, 1);
            if (!(lane & 1))
                h1s[(size_t)r * 8 + (col >> 1)] = pk_bf16(v, oth);
        }
    }
}

// ============ L1: gather agg1 (uniform-shfl broadcast) + ELU + b1 -> x1s bf16 ============
__global__ __launch_bounds__(256) void k_l1(
    const int2* __restrict__ odeg, const int* __restrict__ csr,
    const unsigned* __restrict__ h1s, const float* __restrict__ dinv,
    const float* __restrict__ b1, unsigned* __restrict__ x1s, int N)
{
    const int lane = threadIdx.x & 63;
    const int wid  = threadIdx.x >> 6;
    const int gwave  = blockIdx.x * 4 + wid;
    const int nwaves = gridDim.x * 4;
    const int eg = lane >> 3, w = lane & 7;
    const float b1v = b1[lane & 15];

    for (int n = gwave; n < N; n += nwaves) {
        int2 od = odeg[n];
        int o0 = od.x, cnt = od.y;
        float accx = 0.f, accy = 0.f;
        for (int cb = 0; cb < cnt; cb += 64) {
            int cs = cnt - cb; if (cs > 64) cs = 64;
            int sreg = (lane < cs) ? csr[o0 + cb + lane] : 0;
            #pragma unroll
            for (int i = 0; i < 8; ++i) {      // uniform trip: shfl is exec-uniform
                int e = i * 8 + eg;
                int s = __shfl(sreg, e);
                if (e < cs) {
                    unsigned u = h1s[(size_t)s * 8 + w];
                    accx += bf_lo(u);
                    accy += bf_hi(u);
                }
            }
        }
        accx += __shfl_xor(accx, 8);  accy += __shfl_xor(accy, 8);
        accx += __shfl_xor(accx, 16); accy += __shfl_xor(accy, 16);
        accx += __shfl_xor(accx, 32); accy += __shfl_xor(accy, 32);

        float dv = dinv[n];
        float fx = __shfl(accx, lane >> 1), fy = __shfl(accy, lane >> 1);
        float xv = 0.f;
        if (lane < 16) {
            float aggv = (lane & 1) ? fy : fx;
            unsigned su = h1s[(size_t)n * 8 + (lane >> 1)];
            float self = (lane & 1) ? bf_hi(su) : bf_lo(su);
            xv = (aggv + self) * dv + b1v;
            xv = xv > 0.f ? xv : expm1f(xv);   // elu alpha=1
            xv *= dv;                          // pre-scale by dinv[n] (src-side norm)
        }
        float oth = __shfl_xor(xv, 1);
        if (lane < 16 && !(lane & 1))
            x1s[(size_t)n * 8 + (lane >> 1)] = pk_bf16(xv, oth);
    }
}

// ============ L2: gather agg2 (uniform-shfl broadcast) -> @W2 + b2 + log_softmax ============
__global__ __launch_bounds__(256) void k_l2(
    const int2* __restrict__ odeg, const int* __restrict__ csr,
    const unsigned* __restrict__ x1s, const float* __restrict__ dinv,
    const float* __restrict__ W2, const float* __restrict__ b2,
    float* __restrict__ out, int N)
{
    const int lane = threadIdx.x & 63;
    const int wid  = threadIdx.x >> 6;
    const int gwave  = blockIdx.x * 4 + wid;
    const int nwaves = gridDim.x * 4;
    const int eg = lane >> 3, w = lane & 7;
    const int c = lane < 40 ? lane : 39;

    float w2[16];
    #pragma unroll
    for (int t = 0; t < 16; ++t) w2[t] = W2[t * 40 + c];
    const float b2v = b2[c];

    for (int n = gwave; n < N; n += nwaves) {
        int2 od = odeg[n];
        int o0 = od.x, cnt = od.y;
        float accx = 0.f, accy = 0.f;
        for (int cb = 0; cb < cnt; cb += 64) {
            int cs = cnt - cb; if (cs > 64) cs = 64;
            int sreg = (lane < cs) ? csr[o0 + cb + lane] : 0;
            #pragma unroll
            for (int i = 0; i < 8; ++i) {      // uniform trip: shfl is exec-uniform
                int e = i * 8 + eg;
                int s = __shfl(sreg, e);
                if (e < cs) {
                    unsigned u = x1s[(size_t)s * 8 + w];
                    accx += bf_lo(u);
                    accy += bf_hi(u);
                }
            }
        }
        accx += __shfl_xor(accx, 8);  accy += __shfl_xor(accy, 8);
        accx += __shfl_xor(accx, 16); accy += __shfl_xor(accy, 16);
        accx += __shfl_xor(accx, 32); accy += __shfl_xor(accy, 32);

        float dv = dinv[n];
        float fx = __shfl(accx, lane >> 1), fy = __shfl(accy, lane >> 1);
        float xv = 0.f;
        if (lane < 16) {
            float aggv = (lane & 1) ? fy : fx;
            unsigned su = x1s[(size_t)n * 8 + (lane >> 1)];
            float self = (lane & 1) ? bf_hi(su) : bf_lo(su);
            xv = (aggv + self) * dv;           // 16-dim aggregated x1
        }
        float v = b2v;
        #pragma unroll
        for (int t = 0; t < 16; ++t)
            v = fmaf(__shfl(xv, t), w2[t], v);  // (agg @ W2) + b2, fp32

        float vm = (lane < 40) ? v : -INFINITY;
        #pragma unroll
        for (int off = 32; off; off >>= 1) vm = fmaxf(vm, __shfl_xor(vm, off));
        float ex = (lane < 40) ? expf(v - vm) : 0.f;
        float sum = ex;
        #pragma unroll
        for (int off = 32; off; off >>= 1) sum += __shfl_xor(sum, off);
        if (lane < 40) out[(size_t)n * 40 + lane] = v - vm - logf(sum);
    }
}

extern "C" void kernel_launch(void* const* d_in, const int* in_sizes, int n_in,
                              void* d_out, int out_size, void* d_ws, size_t ws_size,
                              hipStream_t stream) {
    const float* x  = (const float*)d_in[0];
    const float* W1 = (const float*)d_in[1];
    const float* b1 = (const float*)d_in[2];
    const float* W2 = (const float*)d_in[3];
    const float* b2 = (const float*)d_in[4];
    const int*   ei = (const int*)d_in[5];

    const int N = in_sizes[0] / 512;     // 100000 (< 131072; multiple of 16)
    const int E = in_sizes[5] / 2;       // 3200000
    const int* src = ei;
    const int* dst = ei + E;

    const int B     = (N + 127) >> 7;            // 782 buckets
    const int CHUNK = 16384;
    const int NBLK  = (E + CHUNK - 1) / CHUNK;   // 196

    // workspace layout (all 4-byte elems)
    int*      gcur = (int*)d_ws;                         // B (pad 1024)
    unsigned* ebuf = (unsigned*)(gcur + 1024);           // B*CAP  (~25.6MB)
    int*      csr  = (int*)(ebuf + (size_t)B * CAP);     // B*CAP  (~25.6MB)
    int2*     odeg = (int2*)(csr + (size_t)B * CAP);     // N
    float*    dinv = (float*)(odeg + N);                 // N
    unsigned* h1s  = (unsigned*)(dinv + N);              // 8N
    unsigned* x1s  = h1s + (size_t)8 * N;                // 8N
    float*    out  = (float*)d_out;

    hipMemsetAsync(gcur, 0, (size_t)B * sizeof(int), stream);

    k_place1<<<NBLK, 256, 0, stream>>>(src, dst, gcur, ebuf, E, B, CHUNK);
    k_csr   <<<B, 256, 0, stream>>>(gcur, ebuf, csr, odeg, dinv, N);
    k_gemm1 <<<1024, 256, 0, stream>>>(x, W1, dinv, h1s, N);
    // ---- ATTRIBUTION: k_l1 run 5x (idempotent: reads odeg/csr/h1s/dinv/b1, writes x1s).
    // t_l1 = (dur_us - 244.8) / 4. Deterministic; removed next round.
    k_l1    <<<2048, 256, 0, stream>>>(odeg, csr, h1s, dinv, b1, x1s, N);
    k_l1    <<<2048, 256, 0, stream>>>(odeg, csr, h1s, dinv, b1, x1s, N);
    k_l1    <<<2048, 256, 0, stream>>>(odeg, csr, h1s, dinv, b1, x1s, N);
    k_l1    <<<2048, 256, 0, stream>>>(odeg, csr, h1s, dinv, b1, x1s, N);
    k_l1    <<<2048, 256, 0, stream>>>(odeg, csr, h1s, dinv, b1, x1s, N);
    k_l2    <<<2048, 256, 0, stream>>>(odeg, csr, x1s, dinv, W2, b2, out, N);
}

// Round 16
// 375.616 us; speedup vs baseline: 1.0618x; 1.0618x over previous
//
#include <hip/hip_runtime.h>
#include <hip/hip_bf16.h>
#include <math.h>

typedef __attribute__((ext_vector_type(8))) short bf16x8;
typedef __attribute__((ext_vector_type(4))) float f32x4;

#define CAP 8192   // per-bucket capacity (mean 4096, sigma 64 -> no overflow)

// ============ bf16 pack/unpack helpers (bit ops, RNE) ============
__device__ __forceinline__ unsigned pk_bf16(float lo, float hi) {
    unsigned a = __float_as_uint(lo), b = __float_as_uint(hi);
    unsigned alo = (a + 0x7fffu + ((a >> 16) & 1u)) >> 16;
    unsigned bhi = (b + 0x7fffu + ((b >> 16) & 1u)) >> 16;
    return alo | (bhi << 16);
}
__device__ __forceinline__ float bf_lo(unsigned u) { return __uint_as_float(u << 16); }
__device__ __forceinline__ float bf_hi(unsigned u) { return __uint_as_float(u & 0xffff0000u); }

// Bucket = 128 dst nodes. ebuf entry: (dloc<<17) | src   (needs N < 131072)

// ============ ONE-PASS bucketing: LDS hist -> global range-reserve -> scatter ============
__global__ __launch_bounds__(256) void k_place1(
    const int* __restrict__ src, const int* __restrict__ dst,
    int* __restrict__ gcur, unsigned* __restrict__ ebuf,
    int E, int B, int CHUNK)
{
    __shared__ int hist[1024];
    __shared__ int curb[1024];
    int tid = threadIdx.x, b = blockIdx.x;
    for (int j = tid; j < B; j += 256) hist[j] = 0;
    __syncthreads();
    int e0 = b * CHUNK, e1 = min(e0 + CHUNK, E);
    for (int i = e0 + tid * 4; i < e1; i += 1024) {
        if (i + 3 < e1) {
            int4 d4 = *(const int4*)(dst + i);
            atomicAdd(&hist[d4.x >> 7], 1);
            atomicAdd(&hist[d4.y >> 7], 1);
            atomicAdd(&hist[d4.z >> 7], 1);
            atomicAdd(&hist[d4.w >> 7], 1);
        } else {
            for (int k = i; k < e1; ++k) atomicAdd(&hist[dst[k] >> 7], 1);
        }
    }
    __syncthreads();
    for (int j = tid; j < B; j += 256) {
        int h = hist[j];
        curb[j] = h ? atomicAdd(&gcur[j], h) : 0;   // reserve [base, base+h) in bucket j
    }
    __syncthreads();
    for (int i = e0 + tid * 4; i < e1; i += 1024) {
        if (i + 3 < e1) {
            int4 d4 = *(const int4*)(dst + i);
            int4 s4 = *(const int4*)(src + i);
            int p0 = atomicAdd(&curb[d4.x >> 7], 1);
            int p1 = atomicAdd(&curb[d4.y >> 7], 1);
            int p2 = atomicAdd(&curb[d4.z >> 7], 1);
            int p3 = atomicAdd(&curb[d4.w >> 7], 1);
            ebuf[(size_t)(d4.x >> 7) * CAP + p0] = ((unsigned)(d4.x & 127) << 17) | (unsigned)s4.x;
            ebuf[(size_t)(d4.y >> 7) * CAP + p1] = ((unsigned)(d4.y & 127) << 17) | (unsigned)s4.y;
            ebuf[(size_t)(d4.z >> 7) * CAP + p2] = ((unsigned)(d4.z & 127) << 17) | (unsigned)s4.z;
            ebuf[(size_t)(d4.w >> 7) * CAP + p3] = ((unsigned)(d4.w & 127) << 17) | (unsigned)s4.w;
        } else {
            for (int k = i; k < e1; ++k) {
                int d = dst[k], s = src[k];
                int pos = atomicAdd(&curb[d >> 7], 1);
                ebuf[(size_t)(d >> 7) * CAP + pos] = ((unsigned)(d & 127) << 17) | (unsigned)s;
            }
        }
    }
}

// ============ per-bucket CSR build -> csr (CAP-strided), odeg=(offs,deg), dinv ============
__global__ __launch_bounds__(256) void k_csr(
    const int* __restrict__ gcur, const unsigned* __restrict__ ebuf,
    int* __restrict__ csr, int2* __restrict__ odeg,
    float* __restrict__ dinv, int N)
{
    __shared__ int sm[128];
    __shared__ int loc[128];
    int j = blockIdx.x, tid = threadIdx.x;
    int e0 = j * CAP;
    int e1 = e0 + gcur[j];
    if (tid < 128) sm[tid] = 0;
    __syncthreads();
    for (int i = e0 + tid; i < e1; i += 256) atomicAdd(&sm[ebuf[i] >> 17], 1);
    __syncthreads();
    int v = (tid < 128) ? sm[tid] : 0;
    for (int off = 1; off < 128; off <<= 1) {
        int t = (tid < 128 && tid >= off) ? sm[tid - off] : 0;
        __syncthreads();
        if (tid < 128) sm[tid] += t;
        __syncthreads();
    }
    if (tid < 128) {
        int ex = sm[tid] - v;
        loc[tid] = e0 + ex;
        int n = j * 128 + tid;
        if (n < N) {
            odeg[n] = make_int2(e0 + ex, v);
            dinv[n] = rsqrtf((float)v + 1.0f);
        }
    }
    __syncthreads();
    for (int i = e0 + tid; i < e1; i += 256) {
        unsigned eb = ebuf[i];
        int pos = atomicAdd(&loc[eb >> 17], 1);
        csr[pos] = (int)(eb & 0x1FFFFu);
    }
}

// ============ GEMM1 (MFMA, R11 known-good): h1s = (x @ W1) * dinv ============
__global__ __launch_bounds__(256) void k_gemm1(
    const float* __restrict__ x, const float* __restrict__ W1,
    const float* __restrict__ dinv, unsigned* __restrict__ h1s, int N)
{
    const int lane = threadIdx.x & 63;
    const int wid  = threadIdx.x >> 6;
    const int gwave  = blockIdx.x * 4 + wid;
    const int nwaves = gridDim.x * 4;
    const int col = lane & 15;
    const int kg  = lane >> 4;

    unsigned bfr[16][4];
    #pragma unroll
    for (int kk = 0; kk < 16; ++kk) {
        int kbase = kk * 32 + kg * 8;
        #pragma unroll
        for (int i = 0; i < 4; ++i) {
            float lo = W1[(size_t)(kbase + 2 * i) * 16 + col];
            float hi = W1[(size_t)(kbase + 2 * i + 1) * 16 + col];
            bfr[kk][i] = pk_bf16(lo, hi);
        }
    }

    const int TT = N >> 4;
    for (int t = gwave; t < TT; t += nwaves) {
        const float* xr = x + (size_t)(t * 16 + col) * 512 + kg * 8;
        f32x4 acc = {0.f, 0.f, 0.f, 0.f};
        #pragma unroll
        for (int kk = 0; kk < 16; ++kk) {
            float4 xa = *(const float4*)(xr + kk * 32);
            float4 xb = *(const float4*)(xr + kk * 32 + 4);
            unsigned afr[4];
            afr[0] = pk_bf16(xa.x, xa.y);
            afr[1] = pk_bf16(xa.z, xa.w);
            afr[2] = pk_bf16(xb.x, xb.y);
            afr[3] = pk_bf16(xb.z, xb.w);
            acc = __builtin_amdgcn_mfma_f32_16x16x32_bf16(
                *(bf16x8*)afr, *(bf16x8*)&bfr[kk][0], acc, 0, 0, 0);
        }
        #pragma unroll
        for (int m = 0; m < 4; ++m) {
            int r = t * 16 + kg * 4 + m;
            float v = acc[m] * dinv[r];
            float oth = __shfl_xor(v, 1);
            if (!(lane & 1))
                h1s[(size_t)r * 8 + (col >> 1)] = pk_bf16(v, oth);
        }
    }
}

// ============ L1: gather agg1 (uniform-shfl broadcast) + ELU + b1 -> x1s bf16 ============
__global__ __launch_bounds__(256) void k_l1(
    const int2* __restrict__ odeg, const int* __restrict__ csr,
    const unsigned* __restrict__ h1s, const float* __restrict__ dinv,
    const float* __restrict__ b1, unsigned* __restrict__ x1s, int N)
{
    const int lane = threadIdx.x & 63;
    const int wid  = threadIdx.x >> 6;
    const int gwave  = blockIdx.x * 4 + wid;
    const int nwaves = gridDim.x * 4;
    const int eg = lane >> 3, w = lane & 7;
    const float b1v = b1[lane & 15];

    for (int n = gwave; n < N; n += nwaves) {
        int2 od = odeg[n];
        int o0 = od.x, cnt = od.y;
        float accx = 0.f, accy = 0.f;
        for (int cb = 0; cb < cnt; cb += 64) {
            int cs = cnt - cb; if (cs > 64) cs = 64;
            int sreg = (lane < cs) ? csr[o0 + cb + lane] : 0;
            #pragma unroll
            for (int i = 0; i < 8; ++i) {      // uniform trip: shfl is exec-uniform
                int e = i * 8 + eg;
                int s = __shfl(sreg, e);
                if (e < cs) {
                    unsigned u = h1s[(size_t)s * 8 + w];
                    accx += bf_lo(u);
                    accy += bf_hi(u);
                }
            }
        }
        accx += __shfl_xor(accx, 8);  accy += __shfl_xor(accy, 8);
        accx += __shfl_xor(accx, 16); accy += __shfl_xor(accy, 16);
        accx += __shfl_xor(accx, 32); accy += __shfl_xor(accy, 32);

        float dv = dinv[n];
        float fx = __shfl(accx, lane >> 1), fy = __shfl(accy, lane >> 1);
        float xv = 0.f;
        if (lane < 16) {
            float aggv = (lane & 1) ? fy : fx;
            unsigned su = h1s[(size_t)n * 8 + (lane >> 1)];
            float self = (lane & 1) ? bf_hi(su) : bf_lo(su);
            xv = (aggv + self) * dv + b1v;
            xv = xv > 0.f ? xv : expm1f(xv);   // elu alpha=1
            xv *= dv;                          // pre-scale by dinv[n] (src-side norm)
        }
        float oth = __shfl_xor(xv, 1);
        if (lane < 16 && !(lane & 1))
            x1s[(size_t)n * 8 + (lane >> 1)] = pk_bf16(xv, oth);
    }
}

// ============ L2: gather agg2 (uniform-shfl broadcast) -> @W2 + b2 + log_softmax ============
__global__ __launch_bounds__(256) void k_l2(
    const int2* __restrict__ odeg, const int* __restrict__ csr,
    const unsigned* __restrict__ x1s, const float* __restrict__ dinv,
    const float* __restrict__ W2, const float* __restrict__ b2,
    float* __restrict__ out, int N)
{
    const int lane = threadIdx.x & 63;
    const int wid  = threadIdx.x >> 6;
    const int gwave  = blockIdx.x * 4 + wid;
    const int nwaves = gridDim.x * 4;
    const int eg = lane >> 3, w = lane & 7;
    const int c = lane < 40 ? lane : 39;

    float w2[16];
    #pragma unroll
    for (int t = 0; t < 16; ++t) w2[t] = W2[t * 40 + c];
    const float b2v = b2[c];

    for (int n = gwave; n < N; n += nwaves) {
        int2 od = odeg[n];
        int o0 = od.x, cnt = od.y;
        float accx = 0.f, accy = 0.f;
        for (int cb = 0; cb < cnt; cb += 64) {
            int cs = cnt - cb; if (cs > 64) cs = 64;
            int sreg = (lane < cs) ? csr[o0 + cb + lane] : 0;
            #pragma unroll
            for (int i = 0; i < 8; ++i) {      // uniform trip: shfl is exec-uniform
                int e = i * 8 + eg;
                int s = __shfl(sreg, e);
                if (e < cs) {
                    unsigned u = x1s[(size_t)s * 8 + w];
                    accx += bf_lo(u);
                    accy += bf_hi(u);
                }
            }
        }
        accx += __shfl_xor(accx, 8);  accy += __shfl_xor(accy, 8);
        accx += __shfl_xor(accx, 16); accy += __shfl_xor(accy, 16);
        accx += __shfl_xor(accx, 32); accy += __shfl_xor(accy, 32);

        float dv = dinv[n];
        float fx = __shfl(accx, lane >> 1), fy = __shfl(accy, lane >> 1);
        float xv = 0.f;
        if (lane < 16) {
            float aggv = (lane & 1) ? fy : fx;
            unsigned su = x1s[(size_t)n * 8 + (lane >> 1)];
            float self = (lane & 1) ? bf_hi(su) : bf_lo(su);
            xv = (aggv + self) * dv;           // 16-dim aggregated x1
        }
        float v = b2v;
        #pragma unroll
        for (int t = 0; t < 16; ++t)
            v = fmaf(__shfl(xv, t), w2[t], v);  // (agg @ W2) + b2, fp32

        float vm = (lane < 40) ? v : -INFINITY;
        #pragma unroll
        for (int off = 32; off; off >>= 1) vm = fmaxf(vm, __shfl_xor(vm, off));
        float ex = (lane < 40) ? expf(v - vm) : 0.f;
        float sum = ex;
        #pragma unroll
        for (int off = 32; off; off >>= 1) sum += __shfl_xor(sum, off);
        if (lane < 40) out[(size_t)n * 40 + lane] = v - vm - logf(sum);
    }
}

extern "C" void kernel_launch(void* const* d_in, const int* in_sizes, int n_in,
                              void* d_out, int out_size, void* d_ws, size_t ws_size,
                              hipStream_t stream) {
    const float* x  = (const float*)d_in[0];
    const float* W1 = (const float*)d_in[1];
    const float* b1 = (const float*)d_in[2];
    const float* W2 = (const float*)d_in[3];
    const float* b2 = (const float*)d_in[4];
    const int*   ei = (const int*)d_in[5];

    const int N = in_sizes[0] / 512;     // 100000 (< 131072; multiple of 16)
    const int E = in_sizes[5] / 2;       // 3200000
    const int* src = ei;
    const int* dst = ei + E;

    const int B     = (N + 127) >> 7;            // 782 buckets
    const int CHUNK = 16384;
    const int NBLK  = (E + CHUNK - 1) / CHUNK;   // 196

    // workspace layout (all 4-byte elems)
    int*      gcur = (int*)d_ws;                         // B (pad 1024)
    unsigned* ebuf = (unsigned*)(gcur + 1024);           // B*CAP  (~25.6MB)
    int*      csr  = (int*)(ebuf + (size_t)B * CAP);     // B*CAP  (~25.6MB)
    int2*     odeg = (int2*)(csr + (size_t)B * CAP);     // N
    float*    dinv = (float*)(odeg + N);                 // N
    unsigned* h1s  = (unsigned*)(dinv + N);              // 8N
    unsigned* x1s  = h1s + (size_t)8 * N;                // 8N
    float*    out  = (float*)d_out;

    // ---- ATTRIBUTION (unequal multipliers): {memset+place1} x3 total, csr x5 total.
    // Delta = dur - 244.8 = 2*(t_ms + t_place1) + 4*t_csr. Removed next round.
    hipMemsetAsync(gcur, 0, (size_t)B * sizeof(int), stream);
    k_place1<<<NBLK, 256, 0, stream>>>(src, dst, gcur, ebuf, E, B, CHUNK);
    hipMemsetAsync(gcur, 0, (size_t)B * sizeof(int), stream);
    k_place1<<<NBLK, 256, 0, stream>>>(src, dst, gcur, ebuf, E, B, CHUNK);
    hipMemsetAsync(gcur, 0, (size_t)B * sizeof(int), stream);
    k_place1<<<NBLK, 256, 0, stream>>>(src, dst, gcur, ebuf, E, B, CHUNK);

    k_csr   <<<B, 256, 0, stream>>>(gcur, ebuf, csr, odeg, dinv, N);
    k_csr   <<<B, 256, 0, stream>>>(gcur, ebuf, csr, odeg, dinv, N);
    k_csr   <<<B, 256, 0, stream>>>(gcur, ebuf, csr, odeg, dinv, N);
    k_csr   <<<B, 256, 0, stream>>>(gcur, ebuf, csr, odeg, dinv, N);
    k_csr   <<<B, 256, 0, stream>>>(gcur, ebuf, csr, odeg, dinv, N);

    k_gemm1 <<<1024, 256, 0, stream>>>(x, W1, dinv, h1s, N);
    k_l1    <<<2048, 256, 0, stream>>>(odeg, csr, h1s, dinv, b1, x1s, N);
    k_l2    <<<2048, 256, 0, stream>>>(odeg, csr, x1s, dinv, W2, b2, out, N);
}

// Round 17
// 229.807 us; speedup vs baseline: 1.7355x; 1.6345x over previous
//
#include <hip/hip_runtime.h>
#include <hip/hip_bf16.h>
#include <math.h>

typedef __attribute__((ext_vector_type(8))) short bf16x8;
typedef __attribute__((ext_vector_type(4))) float f32x4;

#define CAP 8192   // per-bucket capacity (mean 4096, sigma 64 -> no overflow)

// ============ bf16 pack/unpack helpers (bit ops, RNE) ============
__device__ __forceinline__ unsigned pk_bf16(float lo, float hi) {
    unsigned a = __float_as_uint(lo), b = __float_as_uint(hi);
    unsigned alo = (a + 0x7fffu + ((a >> 16) & 1u)) >> 16;
    unsigned bhi = (b + 0x7fffu + ((b >> 16) & 1u)) >> 16;
    return alo | (bhi << 16);
}
__device__ __forceinline__ float bf_lo(unsigned u) { return __uint_as_float(u << 16); }
__device__ __forceinline__ float bf_hi(unsigned u) { return __uint_as_float(u & 0xffff0000u); }

// Bucket = 128 dst nodes. ebuf entry: (dloc<<17) | src   (needs N < 131072)

// ============ ONE-PASS bucketing: LDS hist -> global range-reserve -> scatter ============
__global__ __launch_bounds__(256) void k_place1(
    const int* __restrict__ src, const int* __restrict__ dst,
    int* __restrict__ gcur, unsigned* __restrict__ ebuf,
    int E, int B, int CHUNK)
{
    __shared__ int hist[1024];
    __shared__ int curb[1024];
    int tid = threadIdx.x, b = blockIdx.x;
    for (int j = tid; j < B; j += 256) hist[j] = 0;
    __syncthreads();
    int e0 = b * CHUNK, e1 = min(e0 + CHUNK, E);
    for (int i = e0 + tid * 4; i < e1; i += 1024) {
        if (i + 3 < e1) {
            int4 d4 = *(const int4*)(dst + i);
            atomicAdd(&hist[d4.x >> 7], 1);
            atomicAdd(&hist[d4.y >> 7], 1);
            atomicAdd(&hist[d4.z >> 7], 1);
            atomicAdd(&hist[d4.w >> 7], 1);
        } else {
            for (int k = i; k < e1; ++k) atomicAdd(&hist[dst[k] >> 7], 1);
        }
    }
    __syncthreads();
    for (int j = tid; j < B; j += 256) {
        int h = hist[j];
        curb[j] = h ? atomicAdd(&gcur[j], h) : 0;   // reserve [base, base+h) in bucket j
    }
    __syncthreads();
    for (int i = e0 + tid * 4; i < e1; i += 1024) {
        if (i + 3 < e1) {
            int4 d4 = *(const int4*)(dst + i);
            int4 s4 = *(const int4*)(src + i);
            int p0 = atomicAdd(&curb[d4.x >> 7], 1);
            int p1 = atomicAdd(&curb[d4.y >> 7], 1);
            int p2 = atomicAdd(&curb[d4.z >> 7], 1);
            int p3 = atomicAdd(&curb[d4.w >> 7], 1);
            ebuf[(size_t)(d4.x >> 7) * CAP + p0] = ((unsigned)(d4.x & 127) << 17) | (unsigned)s4.x;
            ebuf[(size_t)(d4.y >> 7) * CAP + p1] = ((unsigned)(d4.y & 127) << 17) | (unsigned)s4.y;
            ebuf[(size_t)(d4.z >> 7) * CAP + p2] = ((unsigned)(d4.z & 127) << 17) | (unsigned)s4.z;
            ebuf[(size_t)(d4.w >> 7) * CAP + p3] = ((unsigned)(d4.w & 127) << 17) | (unsigned)s4.w;
        } else {
            for (int k = i; k < e1; ++k) {
                int d = dst[k], s = src[k];
                int pos = atomicAdd(&curb[d >> 7], 1);
                ebuf[(size_t)(d >> 7) * CAP + pos] = ((unsigned)(d & 127) << 17) | (unsigned)s;
            }
        }
    }
}

// ============ per-bucket CSR build -> csr (CAP-strided), odeg=(offs,deg), dinv ============
__global__ __launch_bounds__(256) void k_csr(
    const int* __restrict__ gcur, const unsigned* __restrict__ ebuf,
    int* __restrict__ csr, int2* __restrict__ odeg,
    float* __restrict__ dinv, int N)
{
    __shared__ int sm[128];
    __shared__ int loc[128];
    int j = blockIdx.x, tid = threadIdx.x;
    int e0 = j * CAP;
    int e1 = e0 + gcur[j];
    if (tid < 128) sm[tid] = 0;
    __syncthreads();
    for (int i = e0 + tid; i < e1; i += 256) atomicAdd(&sm[ebuf[i] >> 17], 1);
    __syncthreads();
    int v = (tid < 128) ? sm[tid] : 0;
    for (int off = 1; off < 128; off <<= 1) {
        int t = (tid < 128 && tid >= off) ? sm[tid - off] : 0;
        __syncthreads();
        if (tid < 128) sm[tid] += t;
        __syncthreads();
    }
    if (tid < 128) {
        int ex = sm[tid] - v;
        loc[tid] = e0 + ex;
        int n = j * 128 + tid;
        if (n < N) {
            odeg[n] = make_int2(e0 + ex, v);
            dinv[n] = rsqrtf((float)v + 1.0f);
        }
    }
    __syncthreads();
    for (int i = e0 + tid; i < e1; i += 256) {
        unsigned eb = ebuf[i];
        int pos = atomicAdd(&loc[eb >> 17], 1);
        csr[pos] = (int)(eb & 0x1FFFFu);
    }
}

// ============ GEMM1 (MFMA): h1s = (x @ W1) * dinv; exact-fit grid, float4 dinv ============
__global__ __launch_bounds__(256) void k_gemm1(
    const float* __restrict__ x, const float* __restrict__ W1,
    const float* __restrict__ dinv, unsigned* __restrict__ h1s, int N)
{
    const int lane = threadIdx.x & 63;
    const int wid  = threadIdx.x >> 6;
    const int gwave  = blockIdx.x * 4 + wid;
    const int nwaves = gridDim.x * 4;
    const int col = lane & 15;
    const int kg  = lane >> 4;

    unsigned bfr[16][4];
    #pragma unroll
    for (int kk = 0; kk < 16; ++kk) {
        int kbase = kk * 32 + kg * 8;
        #pragma unroll
        for (int i = 0; i < 4; ++i) {
            float lo = W1[(size_t)(kbase + 2 * i) * 16 + col];
            float hi = W1[(size_t)(kbase + 2 * i + 1) * 16 + col];
            bfr[kk][i] = pk_bf16(lo, hi);
        }
    }

    const int TT = N >> 4;
    for (int t = gwave; t < TT; t += nwaves) {
        const float* xr = x + (size_t)(t * 16 + col) * 512 + kg * 8;
        f32x4 acc = {0.f, 0.f, 0.f, 0.f};
        #pragma unroll
        for (int kk = 0; kk < 16; ++kk) {
            float4 xa = *(const float4*)(xr + kk * 32);
            float4 xb = *(const float4*)(xr + kk * 32 + 4);
            unsigned afr[4];
            afr[0] = pk_bf16(xa.x, xa.y);
            afr[1] = pk_bf16(xa.z, xa.w);
            afr[2] = pk_bf16(xb.x, xb.y);
            afr[3] = pk_bf16(xb.z, xb.w);
            acc = __builtin_amdgcn_mfma_f32_16x16x32_bf16(
                *(bf16x8*)afr, *(bf16x8*)&bfr[kk][0], acc, 0, 0, 0);
        }
        float4 dv4 = *(const float4*)(dinv + t * 16 + kg * 4);
        const float* dvp = (const float*)&dv4;
        #pragma unroll
        for (int m = 0; m < 4; ++m) {
            int r = t * 16 + kg * 4 + m;
            float v = acc[m] * dvp[m];
            float oth = __shfl_xor(v, 1);
            if (!(lane & 1))
                h1s[(size_t)r * 8 + (col >> 1)] = pk_bf16(v, oth);
        }
    }
}

// ============ L1: gather agg1 (uniform-shfl, adaptive trips) + ELU + b1 -> x1s ============
__global__ __launch_bounds__(256) void k_l1(
    const int2* __restrict__ odeg, const int* __restrict__ csr,
    const unsigned* __restrict__ h1s, const float* __restrict__ dinv,
    const float* __restrict__ b1, unsigned* __restrict__ x1s, int N)
{
    const int lane = threadIdx.x & 63;
    const int wid  = threadIdx.x >> 6;
    const int gwave  = blockIdx.x * 4 + wid;
    const int nwaves = gridDim.x * 4;
    const int eg = lane >> 3, w = lane & 7;
    const float b1v = b1[lane & 15];

    for (int n = gwave; n < N; n += nwaves) {
        int2 od = odeg[n];
        int o0 = od.x, cnt = od.y;
        float accx = 0.f, accy = 0.f;
        for (int cb = 0; cb < cnt; cb += 64) {
            int cs = cnt - cb; if (cs > 64) cs = 64;
            int sreg = (lane < cs) ? csr[o0 + cb + lane] : 0;
            int iters = (cs + 7) >> 3;         // wave-uniform -> shfl stays exec-uniform
            for (int i = 0; i < iters; ++i) {
                int e = i * 8 + eg;
                int s = __shfl(sreg, e);
                if (e < cs) {
                    unsigned u = h1s[(size_t)s * 8 + w];
                    accx += bf_lo(u);
                    accy += bf_hi(u);
                }
            }
        }
        accx += __shfl_xor(accx, 8);  accy += __shfl_xor(accy, 8);
        accx += __shfl_xor(accx, 16); accy += __shfl_xor(accy, 16);
        accx += __shfl_xor(accx, 32); accy += __shfl_xor(accy, 32);

        float dv = dinv[n];
        float fx = __shfl(accx, lane >> 1), fy = __shfl(accy, lane >> 1);
        float xv = 0.f;
        if (lane < 16) {
            float aggv = (lane & 1) ? fy : fx;
            unsigned su = h1s[(size_t)n * 8 + (lane >> 1)];
            float self = (lane & 1) ? bf_hi(su) : bf_lo(su);
            xv = (aggv + self) * dv + b1v;
            xv = xv > 0.f ? xv : expm1f(xv);   // elu alpha=1
            xv *= dv;                          // pre-scale by dinv[n] (src-side norm)
        }
        float oth = __shfl_xor(xv, 1);
        if (lane < 16 && !(lane & 1))
            x1s[(size_t)n * 8 + (lane >> 1)] = pk_bf16(xv, oth);
    }
}

// ============ L2: gather agg2 (uniform-shfl, adaptive trips) -> @W2 + b2 + lsm ============
__global__ __launch_bounds__(256) void k_l2(
    const int2* __restrict__ odeg, const int* __restrict__ csr,
    const unsigned* __restrict__ x1s, const float* __restrict__ dinv,
    const float* __restrict__ W2, const float* __restrict__ b2,
    float* __restrict__ out, int N)
{
    const int lane = threadIdx.x & 63;
    const int wid  = threadIdx.x >> 6;
    const int gwave  = blockIdx.x * 4 + wid;
    const int nwaves = gridDim.x * 4;
    const int eg = lane >> 3, w = lane & 7;
    const int c = lane < 40 ? lane : 39;

    float w2[16];
    #pragma unroll
    for (int t = 0; t < 16; ++t) w2[t] = W2[t * 40 + c];
    const float b2v = b2[c];

    for (int n = gwave; n < N; n += nwaves) {
        int2 od = odeg[n];
        int o0 = od.x, cnt = od.y;
        float accx = 0.f, accy = 0.f;
        for (int cb = 0; cb < cnt; cb += 64) {
            int cs = cnt - cb; if (cs > 64) cs = 64;
            int sreg = (lane < cs) ? csr[o0 + cb + lane] : 0;
            int iters = (cs + 7) >> 3;         // wave-uniform -> shfl stays exec-uniform
            for (int i = 0; i < iters; ++i) {
                int e = i * 8 + eg;
                int s = __shfl(sreg, e);
                if (e < cs) {
                    unsigned u = x1s[(size_t)s * 8 + w];
                    accx += bf_lo(u);
                    accy += bf_hi(u);
                }
            }
        }
        accx += __shfl_xor(accx, 8);  accy += __shfl_xor(accy, 8);
        accx += __shfl_xor(accx, 16); accy += __shfl_xor(accy, 16);
        accx += __shfl_xor(accx, 32); accy += __shfl_xor(accy, 32);

        float dv = dinv[n];
        float fx = __shfl(accx, lane >> 1), fy = __shfl(accy, lane >> 1);
        float xv = 0.f;
        if (lane < 16) {
            float aggv = (lane & 1) ? fy : fx;
            unsigned su = x1s[(size_t)n * 8 + (lane >> 1)];
            float self = (lane & 1) ? bf_hi(su) : bf_lo(su);
            xv = (aggv + self) * dv;           // 16-dim aggregated x1
        }
        float v = b2v;
        #pragma unroll
        for (int t = 0; t < 16; ++t)
            v = fmaf(__shfl(xv, t), w2[t], v);  // (agg @ W2) + b2, fp32

        float vm = (lane < 40) ? v : -INFINITY;
        #pragma unroll
        for (int off = 32; off; off >>= 1) vm = fmaxf(vm, __shfl_xor(vm, off));
        float ex = (lane < 40) ? expf(v - vm) : 0.f;
        float sum = ex;
        #pragma unroll
        for (int off = 32; off; off >>= 1) sum += __shfl_xor(sum, off);
        if (lane < 40) out[(size_t)n * 40 + lane] = v - vm - logf(sum);
    }
}

extern "C" void kernel_launch(void* const* d_in, const int* in_sizes, int n_in,
                              void* d_out, int out_size, void* d_ws, size_t ws_size,
                              hipStream_t stream) {
    const float* x  = (const float*)d_in[0];
    const float* W1 = (const float*)d_in[1];
    const float* b1 = (const float*)d_in[2];
    const float* W2 = (const float*)d_in[3];
    const float* b2 = (const float*)d_in[4];
    const int*   ei = (const int*)d_in[5];

    const int N = in_sizes[0] / 512;     // 100000 (< 131072; multiple of 16)
    const int E = in_sizes[5] / 2;       // 3200000
    const int* src = ei;
    const int* dst = ei + E;

    const int B     = (N + 127) >> 7;            // 782 buckets
    const int CHUNK = 16384;
    const int NBLK  = (E + CHUNK - 1) / CHUNK;   // 196

    // workspace layout (all 4-byte elems)
    int*      gcur = (int*)d_ws;                         // B (pad 1024)
    unsigned* ebuf = (unsigned*)(gcur + 1024);           // B*CAP  (~25.6MB)
    int*      csr  = (int*)(ebuf + (size_t)B * CAP);     // B*CAP  (~25.6MB)
    int2*     odeg = (int2*)(csr + (size_t)B * CAP);     // N
    float*    dinv = (float*)(odeg + N);                 // N
    unsigned* h1s  = (unsigned*)(dinv + N);              // 8N
    unsigned* x1s  = h1s + (size_t)8 * N;                // 8N
    float*    out  = (float*)d_out;

    const int GB = ((N >> 4) + 3) / 4;           // 1563: exactly 1 tile per wave

    hipMemsetAsync(gcur, 0, (size_t)B * sizeof(int), stream);

    k_place1<<<NBLK, 256, 0, stream>>>(src, dst, gcur, ebuf, E, B, CHUNK);
    k_csr   <<<B, 256, 0, stream>>>(gcur, ebuf, csr, odeg, dinv, N);
    k_gemm1 <<<GB, 256, 0, stream>>>(x, W1, dinv, h1s, N);
    k_l1    <<<2048, 256, 0, stream>>>(odeg, csr, h1s, dinv, b1, x1s, N);
    k_l2    <<<2048, 256, 0, stream>>>(odeg, csr, x1s, dinv, W2, b2, out, N);
}